// Round 13
// baseline (150.176 us; speedup 1.0000x reference)
//
#include <hip/hip_runtime.h>
#include <stdint.h>

#define N_NODES 50000
#define N_EDGES 400000
#define DDIM 256
#define MASK_WORDS 400000  // 50000*256/32
#define EDGE_CAP 64        // padded CSR row capacity (max in-degree ~30)
#define DEG_BLOCKS 1563    // ceil(400000/256)
#define MASK_BLOCKS 1563   // ceil(400000/256)

typedef __attribute__((ext_vector_type(8))) short bf16x8;
typedef __attribute__((ext_vector_type(4))) float f32x4;

// ---------------------------------------------------------------------------
// JAX threefry2x32, key = (0, 42).  Partitionable scheme (verified round 5):
// element with flat index j uses counter (0, j); draw = out0 ^ out1.
// ---------------------------------------------------------------------------
__device__ __forceinline__ uint32_t rotl32(uint32_t x, uint32_t r) {
  return (x << r) | (x >> (32u - r));
}

__device__ __forceinline__ uint32_t threefry_draw_0_42(uint32_t x0, uint32_t x1) {
  const uint32_t k0 = 0u, k1 = 42u;
  const uint32_t k2 = k0 ^ k1 ^ 0x1BD11BDAu;
  x0 += k0;
  x1 += k1;
#define TF_ROUND(r)          \
  {                          \
    x0 += x1;                \
    x1 = rotl32(x1, r);      \
    x1 ^= x0;                \
  }
  TF_ROUND(13) TF_ROUND(15) TF_ROUND(26) TF_ROUND(6)
  x0 += k1; x1 += k2 + 1u;
  TF_ROUND(17) TF_ROUND(29) TF_ROUND(16) TF_ROUND(24)
  x0 += k2; x1 += k0 + 2u;
  TF_ROUND(13) TF_ROUND(15) TF_ROUND(26) TF_ROUND(6)
  x0 += k0; x1 += k1 + 3u;
  TF_ROUND(17) TF_ROUND(29) TF_ROUND(16) TF_ROUND(24)
  x0 += k1; x1 += k2 + 4u;
  TF_ROUND(13) TF_ROUND(15) TF_ROUND(26) TF_ROUND(6)
  x0 += k2; x1 += k0 + 5u;
#undef TF_ROUND
  return x0 ^ x1;
}

__device__ __forceinline__ uint16_t bf16_rne(float x) {
  uint32_t u = __float_as_uint(x);
  u += 0x7FFFu + ((u >> 16) & 1u);
  return (uint16_t)(u >> 16);
}

__device__ __forceinline__ float bf16_to_f32(uint16_t x) {
  return __uint_as_float(((uint32_t)x) << 16);
}

// ---------------------------------------------------------------------------
// 1) setup: blocks 0-97 zero deg_out+deg_in (25000 int4);
//           blocks 98-161 transpose W fp32 [k][n] -> Wt bf16 [n][k]
// ---------------------------------------------------------------------------
__global__ __launch_bounds__(256) void setup_kernel(
    const float* __restrict__ W, uint16_t* __restrict__ Wt,
    int4* __restrict__ zero_base) {
  const int bid = blockIdx.x;
  if (bid < 98) {
    const int t = bid * 256 + threadIdx.x;
    if (t < 25000) zero_base[t] = make_int4(0, 0, 0, 0);
  } else {
    const int t = (bid - 98) * 256 + threadIdx.x;  // 0..16383
    const int n = t >> 6;
    const int k4 = (t & 63) << 2;
    ushort4 p;
    p.x = bf16_rne(W[(size_t)(k4 + 0) * DDIM + n]);
    p.y = bf16_rne(W[(size_t)(k4 + 1) * DDIM + n]);
    p.z = bf16_rne(W[(size_t)(k4 + 2) * DDIM + n]);
    p.w = bf16_rne(W[(size_t)(k4 + 3) * DDIM + n]);
    *(ushort4*)(Wt + (size_t)n * DDIM + k4) = p;
  }
}

// ---------------------------------------------------------------------------
// 2) degree+fill (blocks 0..1562) fused with dropout-mask gen (blocks
//    1563..3125).  Mask is pure VALU and overlaps the atomic-latency blocks.
//    deg_in's atomic counter doubles as the padded-CSR insertion cursor.
// ---------------------------------------------------------------------------
__global__ __launch_bounds__(256) void degree_fill_mask_kernel(
    const int* __restrict__ src, const int* __restrict__ dst,
    int* __restrict__ deg_out, int* __restrict__ deg_in,
    int* __restrict__ esrc, uint32_t* __restrict__ mask) {
  const int bid = blockIdx.x;
  if (bid < DEG_BLOCKS) {
    const int e = bid * 256 + threadIdx.x;
    if (e < N_EDGES) {
      const int s = src[e];
      const int d = dst[e];
      atomicAdd(&deg_out[s], 1);
      const int pos = atomicAdd(&deg_in[d], 1);
      if (pos < EDGE_CAP) esrc[(d << 6) + pos] = s;  // never overflows (max~30)
    }
  } else {
    const uint32_t t = (uint32_t)(bid - DEG_BLOCKS) * 256u + (uint32_t)threadIdx.x;
    if (t < MASK_WORDS) {
      const uint32_t base = t * 32u;
      uint32_t w = 0u;
#pragma unroll
      for (uint32_t b = 0; b < 32u; ++b) {
        const uint32_t bits = threefry_draw_0_42(0u, base + b);
        w |= ((bits >> 9) < 7549747u) ? (1u << b) : 0u;  // u<0.9f exactly
      }
      mask[t] = w;
    }
  }
}

// ---------------------------------------------------------------------------
// 3) featb = bf16(feat * rsqrt(max(deg_out,1)))  (pre-scaled, into ws)
// ---------------------------------------------------------------------------
__global__ __launch_bounds__(256) void fconv_kernel(
    const float* __restrict__ feat, const int* __restrict__ deg_out,
    uint16_t* __restrict__ featb) {
  const int t = blockIdx.x * 256 + threadIdx.x;
  const size_t base = (size_t)t * 8;
  const int row = t >> 5;  // 256 elems/row, 8/thread -> 32 threads/row
  const float sc = rsqrtf(fmaxf((float)deg_out[row], 1.0f));
  const float4 a = *(const float4*)(feat + base);
  const float4 b = *(const float4*)(feat + base + 4);
  ushort4 lo, hi;
  lo.x = bf16_rne(a.x * sc); lo.y = bf16_rne(a.y * sc);
  lo.z = bf16_rne(a.z * sc); lo.w = bf16_rne(a.w * sc);
  hi.x = bf16_rne(b.x * sc); hi.y = bf16_rne(b.y * sc);
  hi.z = bf16_rne(b.z * sc); hi.w = bf16_rne(b.w * sc);
  *(ushort4*)(featb + base) = lo;
  *(ushort4*)(featb + base + 4) = hi;
}

// ---------------------------------------------------------------------------
// 4) FUSED gather + gemm + epilogue.
//    Block = 64 output rows x 256 cols, 4 waves.
//    Phase A (gather): wave w aggregates nodes r0+16w .. r0+16w+15 (x4-
//    unrolled edge loop over padded CSR, fp32 accum, all 64 lanes on one
//    node row) and writes bf16 directly into the LDS A panel.
//    Phase B: 16x16x32 MFMA over As x Wt (B direct from L2), then
//    rsqrt(deg_in)*+bias, relu, mask-bit dropout -> out.
// ---------------------------------------------------------------------------
#define APAD 280  // shorts per As row (560 B, 16B-aligned)
__global__ __launch_bounds__(256, 4) void gather_gemm_kernel(
    const uint16_t* __restrict__ featb, const int* __restrict__ deg_in,
    const int* __restrict__ esrc, const uint16_t* __restrict__ Wt,
    const float* __restrict__ bias, const uint32_t* __restrict__ mask,
    float* __restrict__ out) {
  __shared__ short As[64 * APAD];
  __shared__ float sdeg[64];
  __shared__ float sbias[256];

  const int tid = threadIdx.x;
  const int r0 = blockIdx.x * 64;
  const int lane = tid & 63;
  const int wv = tid >> 6;  // wave id; also col-panel in phase B
  const int seg = lane >> 4;
  const int l15 = lane & 15;

  sbias[tid] = bias[tid];
  if (tid < 64) {
    const int r = r0 + tid;
    sdeg[tid] = (r < N_NODES) ? rsqrtf(fmaxf((float)deg_in[r], 1.0f)) : 0.0f;
  }

  // ---- Phase A: gather 16 rows per wave into As ----
  const size_t off = (size_t)(lane << 2);
  for (int i = 0; i < 16; ++i) {
    const int lrow = wv * 16 + i;
    const int n = r0 + lrow;
    float4 a0 = {0.f, 0.f, 0.f, 0.f}, a1 = a0, a2 = a0, a3 = a0;
    if (n < N_NODES) {
      const int beg = n << 6;
      const int fin = beg + min(deg_in[n], EDGE_CAP);
      int j = beg;
      for (; j + 4 <= fin; j += 4) {
        const int s0 = esrc[j + 0];
        const int s1 = esrc[j + 1];
        const int s2 = esrc[j + 2];
        const int s3 = esrc[j + 3];
        const ushort4 q0 = *(const ushort4*)(featb + (size_t)s0 * DDIM + off);
        const ushort4 q1 = *(const ushort4*)(featb + (size_t)s1 * DDIM + off);
        const ushort4 q2 = *(const ushort4*)(featb + (size_t)s2 * DDIM + off);
        const ushort4 q3 = *(const ushort4*)(featb + (size_t)s3 * DDIM + off);
        a0.x += bf16_to_f32(q0.x); a0.y += bf16_to_f32(q0.y);
        a0.z += bf16_to_f32(q0.z); a0.w += bf16_to_f32(q0.w);
        a1.x += bf16_to_f32(q1.x); a1.y += bf16_to_f32(q1.y);
        a1.z += bf16_to_f32(q1.z); a1.w += bf16_to_f32(q1.w);
        a2.x += bf16_to_f32(q2.x); a2.y += bf16_to_f32(q2.y);
        a2.z += bf16_to_f32(q2.z); a2.w += bf16_to_f32(q2.w);
        a3.x += bf16_to_f32(q3.x); a3.y += bf16_to_f32(q3.y);
        a3.z += bf16_to_f32(q3.z); a3.w += bf16_to_f32(q3.w);
      }
      for (; j < fin; ++j) {
        const int s = esrc[j];
        const ushort4 q = *(const ushort4*)(featb + (size_t)s * DDIM + off);
        a0.x += bf16_to_f32(q.x); a0.y += bf16_to_f32(q.y);
        a0.z += bf16_to_f32(q.z); a0.w += bf16_to_f32(q.w);
      }
    }
    ushort4 p;
    p.x = bf16_rne((a0.x + a1.x) + (a2.x + a3.x));
    p.y = bf16_rne((a0.y + a1.y) + (a2.y + a3.y));
    p.z = bf16_rne((a0.z + a1.z) + (a2.z + a3.z));
    p.w = bf16_rne((a0.w + a1.w) + (a2.w + a3.w));
    *(ushort4*)&As[lrow * APAD + (lane << 2)] = p;
  }
  __syncthreads();

  // ---- Phase B: MFMA + epilogue ----
  const uint16_t* wt_base = Wt + (size_t)(wv * 64 + l15) * DDIM + seg * 8;

  f32x4 acc[4][4] = {};
#pragma unroll
  for (int kkI = 0; kkI < 8; ++kkI) {
    const int kk = kkI * 32;
    bf16x8 a[4], b[4];
#pragma unroll
    for (int m = 0; m < 4; ++m)
      a[m] = *(const bf16x8*)&As[(m * 16 + l15) * APAD + kk + seg * 8];
#pragma unroll
    for (int n = 0; n < 4; ++n)
      b[n] = *(const bf16x8*)(wt_base + n * 16 * DDIM + kk);
#pragma unroll
    for (int m = 0; m < 4; ++m)
#pragma unroll
      for (int n = 0; n < 4; ++n)
        acc[m][n] = __builtin_amdgcn_mfma_f32_16x16x32_bf16(a[m], b[n], acc[m][n], 0, 0, 0);
  }

  // C/D layout: col = lane&15, row = seg*4 + reg
  constexpr float INV09 = 1.0f / 0.9f;
#pragma unroll
  for (int m = 0; m < 4; ++m) {
#pragma unroll
    for (int r = 0; r < 4; ++r) {
      const int lrow = m * 16 + seg * 4 + r;
      const int row = r0 + lrow;
      if (row >= N_NODES) continue;
      const float s = sdeg[lrow];
      const uint32_t w0 = mask[row * 8 + wv * 2];      // cols wv*64 .. +31
      const uint32_t w1 = mask[row * 8 + wv * 2 + 1];  // cols wv*64+32 .. +63
#pragma unroll
      for (int n = 0; n < 4; ++n) {
        const int col = wv * 64 + n * 16 + l15;
        float v = fmaxf(acc[m][n][r] * s + sbias[col], 0.0f);
        const uint32_t w = (n < 2) ? w0 : w1;
        const uint32_t bit = (uint32_t)((n & 1) * 16 + l15);
        out[(size_t)row * DDIM + col] = ((w >> bit) & 1u) ? v * INV09 : 0.0f;
      }
    }
  }
}

// ---------------------------------------------------------------------------
// ws layout (bytes; ws_size ~268 MB per harness poison fill):
//   deg_out   @ 0          (200000)
//   deg_in    @ 200000     (200000)
//   esrc      @ 400000     (12800000)  padded CSR [n][64]
//   Wt bf16   @ 13200000   (131072)
//   featb bf16@ 13331072   (25600000)  <- moved from d_out (fused kernel
//                                         reads featb while writing out)
//   mask u32  @ 38931072   (1600000)   total ~40.5 MB
// ---------------------------------------------------------------------------
extern "C" void kernel_launch(void* const* d_in, const int* in_sizes, int n_in,
                              void* d_out, int out_size, void* d_ws, size_t ws_size,
                              hipStream_t stream) {
  const float* feat = (const float*)d_in[0];
  const float* W = (const float*)d_in[1];
  const float* bias = (const float*)d_in[2];
  const int* src = (const int*)d_in[3];
  const int* dst = (const int*)d_in[4];
  float* out = (float*)d_out;

  char* ws = (char*)d_ws;
  int* deg_out = (int*)(ws + 0);
  int* deg_in = (int*)(ws + 200000);
  int* esrc = (int*)(ws + 400000);
  uint16_t* Wt = (uint16_t*)(ws + 13200000);
  uint16_t* featb = (uint16_t*)(ws + 13331072);
  uint32_t* mask = (uint32_t*)(ws + 38931072);

  setup_kernel<<<162, 256, 0, stream>>>(W, Wt, (int4*)d_ws);
  degree_fill_mask_kernel<<<DEG_BLOCKS + MASK_BLOCKS, 256, 0, stream>>>(
      src, dst, deg_out, deg_in, esrc, mask);
  fconv_kernel<<<6250, 256, 0, stream>>>(feat, deg_out, featb);
  gather_gemm_kernel<<<(N_NODES + 63) / 64, 256, 0, stream>>>(
      featb, deg_in, esrc, Wt, bias, mask, out);
}

// Round 14
// 146.962 us; speedup vs baseline: 1.0219x; 1.0219x over previous
//
#include <hip/hip_runtime.h>
#include <stdint.h>

#define N_NODES 50000
#define N_EDGES 400000
#define DDIM 256
#define MASK_WORDS 400000  // 50000*256/32
#define EDGE_CAP 64        // padded CSR row capacity (max in-degree ~30)
#define DEG_BLOCKS 1563    // ceil(400000/256)

typedef __attribute__((ext_vector_type(8))) short bf16x8;
typedef __attribute__((ext_vector_type(4))) float f32x4;

// ---------------------------------------------------------------------------
// JAX threefry2x32, key = (0, 42).  Partitionable scheme (verified round 5):
// element with flat index j uses counter (0, j); draw = out0 ^ out1.
// ---------------------------------------------------------------------------
__device__ __forceinline__ uint32_t rotl32(uint32_t x, uint32_t r) {
  return (x << r) | (x >> (32u - r));
}

__device__ __forceinline__ uint32_t threefry_draw_0_42(uint32_t x0, uint32_t x1) {
  const uint32_t k0 = 0u, k1 = 42u;
  const uint32_t k2 = k0 ^ k1 ^ 0x1BD11BDAu;
  x0 += k0;
  x1 += k1;
#define TF_ROUND(r)          \
  {                          \
    x0 += x1;                \
    x1 = rotl32(x1, r);      \
    x1 ^= x0;                \
  }
  TF_ROUND(13) TF_ROUND(15) TF_ROUND(26) TF_ROUND(6)
  x0 += k1; x1 += k2 + 1u;
  TF_ROUND(17) TF_ROUND(29) TF_ROUND(16) TF_ROUND(24)
  x0 += k2; x1 += k0 + 2u;
  TF_ROUND(13) TF_ROUND(15) TF_ROUND(26) TF_ROUND(6)
  x0 += k0; x1 += k1 + 3u;
  TF_ROUND(17) TF_ROUND(29) TF_ROUND(16) TF_ROUND(24)
  x0 += k1; x1 += k2 + 4u;
  TF_ROUND(13) TF_ROUND(15) TF_ROUND(26) TF_ROUND(6)
  x0 += k2; x1 += k0 + 5u;
#undef TF_ROUND
  return x0 ^ x1;
}

__device__ __forceinline__ uint16_t bf16_rne(float x) {
  uint32_t u = __float_as_uint(x);
  u += 0x7FFFu + ((u >> 16) & 1u);
  return (uint16_t)(u >> 16);
}

__device__ __forceinline__ float bf16_to_f32(uint16_t x) {
  return __uint_as_float(((uint32_t)x) << 16);
}

// ---------------------------------------------------------------------------
// 1) setup: blocks 0-97 zero deg_out+deg_in (25000 int4);
//           blocks 98-161 transpose W fp32 [k][n] -> Wt bf16 [n][k]
// ---------------------------------------------------------------------------
__global__ __launch_bounds__(256) void setup_kernel(
    const float* __restrict__ W, uint16_t* __restrict__ Wt,
    int4* __restrict__ zero_base) {
  const int bid = blockIdx.x;
  if (bid < 98) {
    const int t = bid * 256 + threadIdx.x;
    if (t < 25000) zero_base[t] = make_int4(0, 0, 0, 0);
  } else {
    const int t = (bid - 98) * 256 + threadIdx.x;  // 0..16383
    const int n = t >> 6;
    const int k4 = (t & 63) << 2;
    ushort4 p;
    p.x = bf16_rne(W[(size_t)(k4 + 0) * DDIM + n]);
    p.y = bf16_rne(W[(size_t)(k4 + 1) * DDIM + n]);
    p.z = bf16_rne(W[(size_t)(k4 + 2) * DDIM + n]);
    p.w = bf16_rne(W[(size_t)(k4 + 3) * DDIM + n]);
    *(ushort4*)(Wt + (size_t)n * DDIM + k4) = p;
  }
}

// ---------------------------------------------------------------------------
// 2) degree+fill (blocks 0..1562) fused with dropout-mask gen (blocks
//    1563..3125).  Mask is pure VALU and overlaps the atomic-latency blocks.
// ---------------------------------------------------------------------------
__global__ __launch_bounds__(256) void degree_fill_mask_kernel(
    const int* __restrict__ src, const int* __restrict__ dst,
    int* __restrict__ deg_out, int* __restrict__ deg_in,
    int* __restrict__ esrc, uint32_t* __restrict__ mask) {
  const int bid = blockIdx.x;
  if (bid < DEG_BLOCKS) {
    const int e = bid * 256 + threadIdx.x;
    if (e < N_EDGES) {
      const int s = src[e];
      const int d = dst[e];
      atomicAdd(&deg_out[s], 1);
      const int pos = atomicAdd(&deg_in[d], 1);
      if (pos < EDGE_CAP) esrc[(d << 6) + pos] = s;  // never overflows (max~30)
    }
  } else {
    const uint32_t t = (uint32_t)(bid - DEG_BLOCKS) * 256u + (uint32_t)threadIdx.x;
    if (t < MASK_WORDS) {
      const uint32_t base = t * 32u;
      uint32_t w = 0u;
#pragma unroll
      for (uint32_t b = 0; b < 32u; ++b) {
        const uint32_t bits = threefry_draw_0_42(0u, base + b);
        w |= ((bits >> 9) < 7549747u) ? (1u << b) : 0u;  // u<0.9f exactly
      }
      mask[t] = w;
    }
  }
}

// ---------------------------------------------------------------------------
// 3) featb = bf16(feat * rsqrt(max(deg_out,1)))  (pre-scaled, into ws)
// ---------------------------------------------------------------------------
__global__ __launch_bounds__(256) void fconv_kernel(
    const float* __restrict__ feat, const int* __restrict__ deg_out,
    uint16_t* __restrict__ featb) {
  const int t = blockIdx.x * 256 + threadIdx.x;
  const size_t base = (size_t)t * 8;
  const int row = t >> 5;  // 256 elems/row, 8/thread -> 32 threads/row
  const float sc = rsqrtf(fmaxf((float)deg_out[row], 1.0f));
  const float4 a = *(const float4*)(feat + base);
  const float4 b = *(const float4*)(feat + base + 4);
  ushort4 lo, hi;
  lo.x = bf16_rne(a.x * sc); lo.y = bf16_rne(a.y * sc);
  lo.z = bf16_rne(a.z * sc); lo.w = bf16_rne(a.w * sc);
  hi.x = bf16_rne(b.x * sc); hi.y = bf16_rne(b.y * sc);
  hi.z = bf16_rne(b.z * sc); hi.w = bf16_rne(b.w * sc);
  *(ushort4*)(featb + base) = lo;
  *(ushort4*)(featb + base + 4) = hi;
}

// ---------------------------------------------------------------------------
// 4) pull-mode aggregate, 2-edges-per-instruction layout:
//    lanes 0-31 handle edge a, lanes 32-63 edge b; each lane loads uint4
//    (8 bf16 = 16B) of its edge's feature row.  4-deep unroll -> 8 edges /
//    4 KB in flight per wave.  Cross-half __shfl_xor(32) reduce at the end;
//    lanes 0-31 store the 512B bf16 row.
// ---------------------------------------------------------------------------
__device__ __forceinline__ void acc8(float* a, uint4 q) {
  a[0] += __uint_as_float(q.x << 16);
  a[1] += __uint_as_float(q.x & 0xFFFF0000u);
  a[2] += __uint_as_float(q.y << 16);
  a[3] += __uint_as_float(q.y & 0xFFFF0000u);
  a[4] += __uint_as_float(q.z << 16);
  a[5] += __uint_as_float(q.z & 0xFFFF0000u);
  a[6] += __uint_as_float(q.w << 16);
  a[7] += __uint_as_float(q.w & 0xFFFF0000u);
}

__global__ __launch_bounds__(256) void gather_kernel(
    const uint16_t* __restrict__ featb, const int* __restrict__ deg_in,
    const int* __restrict__ esrc, uint16_t* __restrict__ agg) {
  const int n = blockIdx.x * 4 + (threadIdx.x >> 6);
  if (n >= N_NODES) return;
  const int lane = threadIdx.x & 63;
  const int eh = lane >> 5;   // edge slot within pair
  const int l32 = lane & 31;  // column octet
  const size_t coff = (size_t)(l32 << 3);
  const int beg = n << 6;
  const int cnt = min(deg_in[n], EDGE_CAP);

  float a0[8] = {}, a1[8] = {}, a2[8] = {}, a3[8] = {};
  int j = 0;
  for (; j + 8 <= cnt; j += 8) {
    const int s0 = esrc[beg + j + 0 + eh];
    const int s1 = esrc[beg + j + 2 + eh];
    const int s2 = esrc[beg + j + 4 + eh];
    const int s3 = esrc[beg + j + 6 + eh];
    const uint4 q0 = *(const uint4*)(featb + (size_t)s0 * DDIM + coff);
    const uint4 q1 = *(const uint4*)(featb + (size_t)s1 * DDIM + coff);
    const uint4 q2 = *(const uint4*)(featb + (size_t)s2 * DDIM + coff);
    const uint4 q3 = *(const uint4*)(featb + (size_t)s3 * DDIM + coff);
    acc8(a0, q0);
    acc8(a1, q1);
    acc8(a2, q2);
    acc8(a3, q3);
  }
  for (; j + 2 <= cnt; j += 2) {
    const int s = esrc[beg + j + eh];
    const uint4 q = *(const uint4*)(featb + (size_t)s * DDIM + coff);
    acc8(a0, q);
  }
  if (j < cnt && eh == 0) {  // odd tail: half-wave loads the last edge
    const int s = esrc[beg + j];
    const uint4 q = *(const uint4*)(featb + (size_t)s * DDIM + coff);
    acc8(a0, q);
  }

  uint4 p;
  uint32_t pk[4];
#pragma unroll
  for (int k = 0; k < 8; k += 2) {
    float lo = (a0[k] + a1[k]) + (a2[k] + a3[k]);
    float hi = (a0[k + 1] + a1[k + 1]) + (a2[k + 1] + a3[k + 1]);
    lo += __shfl_xor(lo, 32);
    hi += __shfl_xor(hi, 32);
    pk[k >> 1] = (uint32_t)bf16_rne(lo) | ((uint32_t)bf16_rne(hi) << 16);
  }
  p.x = pk[0]; p.y = pk[1]; p.z = pk[2]; p.w = pk[3];
  if (eh == 0) *(uint4*)(agg + (size_t)n * DDIM + coff) = p;
}

// ---------------------------------------------------------------------------
// 5) out = dropout(relu((agg @ W) * rsqrt(max(deg_in,1)) + b))
//    MFMA bf16 16x16x32.  Block = 64 rows x 256 cols, 4 waves (wave: 64x64).
//    A staged once in LDS (37 KB -> 4 blocks/CU); B direct from L2 Wt.
// ---------------------------------------------------------------------------
#define APAD 280  // shorts per As row (560 B, 16B-aligned)
__global__ __launch_bounds__(256, 4) void gemm_mfma_kernel(
    const uint16_t* __restrict__ agg, const uint16_t* __restrict__ Wt,
    const float* __restrict__ bias, const int* __restrict__ deg_in,
    const uint32_t* __restrict__ mask, float* __restrict__ out) {
  __shared__ short As[64 * APAD];
  __shared__ float sdeg[64];
  __shared__ float sbias[256];

  const int tid = threadIdx.x;
  const int r0 = blockIdx.x * 64;
  const int lane = tid & 63;
  const int seg = lane >> 4;  // k-segment 0..3
  const int l15 = lane & 15;
  const int wc = tid >> 6;  // wave -> col panel (64 cols each)

  sbias[tid] = bias[tid];
  if (tid < 64) {
    const int r = r0 + tid;
    sdeg[tid] = (r < N_NODES) ? rsqrtf(fmaxf((float)deg_in[r], 1.0f)) : 0.0f;
  }

  // stage A panel: 64 rows x 256 k bf16 (2048 x 16B chunks, coalesced)
  {
    const uint16_t* ap = agg + (size_t)r0 * DDIM;
#pragma unroll
    for (int it = 0; it < 8; ++it) {
      const int c = tid + 256 * it;
      const int row = c >> 5;        // 32 chunks per row
      const int k8 = (c & 31) << 3;  // 0,8,...,248
      int4 v = make_int4(0, 0, 0, 0);
      if (r0 + row < N_NODES) v = *(const int4*)(ap + (size_t)row * DDIM + k8);
      *(int4*)&As[row * APAD + k8] = v;
    }
  }
  __syncthreads();

  const uint16_t* wt_base = Wt + (size_t)(wc * 64 + l15) * DDIM + seg * 8;

  f32x4 acc[4][4] = {};
#pragma unroll
  for (int kkI = 0; kkI < 8; ++kkI) {
    const int kk = kkI * 32;
    bf16x8 a[4], b[4];
#pragma unroll
    for (int m = 0; m < 4; ++m)
      a[m] = *(const bf16x8*)&As[(m * 16 + l15) * APAD + kk + seg * 8];
#pragma unroll
    for (int n = 0; n < 4; ++n)
      b[n] = *(const bf16x8*)(wt_base + n * 16 * DDIM + kk);
#pragma unroll
    for (int m = 0; m < 4; ++m)
#pragma unroll
      for (int n = 0; n < 4; ++n)
        acc[m][n] = __builtin_amdgcn_mfma_f32_16x16x32_bf16(a[m], b[n], acc[m][n], 0, 0, 0);
  }

  // epilogue: C/D layout col = lane&15, row = seg*4 + reg
  constexpr float INV09 = 1.0f / 0.9f;
#pragma unroll
  for (int m = 0; m < 4; ++m) {
#pragma unroll
    for (int r = 0; r < 4; ++r) {
      const int lrow = m * 16 + seg * 4 + r;
      const int row = r0 + lrow;
      if (row >= N_NODES) continue;
      const float s = sdeg[lrow];
      const uint32_t w0 = mask[row * 8 + wc * 2];      // cols wc*64 .. +31
      const uint32_t w1 = mask[row * 8 + wc * 2 + 1];  // cols wc*64+32 .. +63
#pragma unroll
      for (int n = 0; n < 4; ++n) {
        const int col = wc * 64 + n * 16 + l15;
        float v = fmaxf(acc[m][n][r] * s + sbias[col], 0.0f);
        const uint32_t w = (n < 2) ? w0 : w1;
        const uint32_t bit = (uint32_t)((n & 1) * 16 + l15);
        out[(size_t)row * DDIM + col] = ((w >> bit) & 1u) ? v * INV09 : 0.0f;
      }
    }
  }
}

// ---------------------------------------------------------------------------
// ws layout (bytes; ws_size ~268 MB per harness poison fill):
//   deg_out   @ 0          (200000)
//   deg_in    @ 200000     (200000)
//   esrc      @ 400000     (12800000)  padded CSR [n][64]
//   Wt bf16   @ 13200000   (131072)
//   featb bf16@ 13331072   (25600000)
//   mask u32  @ 38931072   (1600000)
//   agg bf16  @ 40531072   (25600000)  total ~66 MB
// ---------------------------------------------------------------------------
extern "C" void kernel_launch(void* const* d_in, const int* in_sizes, int n_in,
                              void* d_out, int out_size, void* d_ws, size_t ws_size,
                              hipStream_t stream) {
  const float* feat = (const float*)d_in[0];
  const float* W = (const float*)d_in[1];
  const float* bias = (const float*)d_in[2];
  const int* src = (const int*)d_in[3];
  const int* dst = (const int*)d_in[4];
  float* out = (float*)d_out;

  char* ws = (char*)d_ws;
  int* deg_out = (int*)(ws + 0);
  int* deg_in = (int*)(ws + 200000);
  int* esrc = (int*)(ws + 400000);
  uint16_t* Wt = (uint16_t*)(ws + 13200000);
  uint16_t* featb = (uint16_t*)(ws + 13331072);
  uint32_t* mask = (uint32_t*)(ws + 38931072);
  uint16_t* agg = (uint16_t*)(ws + 40531072);

  setup_kernel<<<162, 256, 0, stream>>>(W, Wt, (int4*)d_ws);
  degree_fill_mask_kernel<<<DEG_BLOCKS + 1563, 256, 0, stream>>>(
      src, dst, deg_out, deg_in, esrc, mask);
  fconv_kernel<<<6250, 256, 0, stream>>>(feat, deg_out, featb);
  gather_kernel<<<(N_NODES + 3) / 4, 256, 0, stream>>>(featb, deg_in, esrc, agg);
  gemm_mfma_kernel<<<(N_NODES + 63) / 64, 256, 0, stream>>>(agg, Wt, bias, deg_in, mask, out);
}

// Round 15
// 129.665 us; speedup vs baseline: 1.1582x; 1.1334x over previous
//
#include <hip/hip_runtime.h>
#include <stdint.h>

#define N_NODES 50000
#define N_EDGES 400000
#define DDIM 256
#define MASK_WORDS 400000  // 50000*256/32
#define EDGE_CAP 64        // padded CSR row capacity (max in-degree ~30)
#define FCONV_BLOCKS 6250  // 50000*256/8 / 256
#define FILL_BLOCKS 391    // ceil(100000/256), 4 edges per thread
#define MASK_BLOCKS 1563   // ceil(400000/256)

typedef __attribute__((ext_vector_type(8))) short bf16x8;
typedef __attribute__((ext_vector_type(4))) float f32x4;

// ---------------------------------------------------------------------------
// JAX threefry2x32, key = (0, 42).  Partitionable scheme (verified round 5):
// element with flat index j uses counter (0, j); draw = out0 ^ out1.
// ---------------------------------------------------------------------------
__device__ __forceinline__ uint32_t rotl32(uint32_t x, uint32_t r) {
  return (x << r) | (x >> (32u - r));
}

__device__ __forceinline__ uint32_t threefry_draw_0_42(uint32_t x0, uint32_t x1) {
  const uint32_t k0 = 0u, k1 = 42u;
  const uint32_t k2 = k0 ^ k1 ^ 0x1BD11BDAu;
  x0 += k0;
  x1 += k1;
#define TF_ROUND(r)          \
  {                          \
    x0 += x1;                \
    x1 = rotl32(x1, r);      \
    x1 ^= x0;                \
  }
  TF_ROUND(13) TF_ROUND(15) TF_ROUND(26) TF_ROUND(6)
  x0 += k1; x1 += k2 + 1u;
  TF_ROUND(17) TF_ROUND(29) TF_ROUND(16) TF_ROUND(24)
  x0 += k2; x1 += k0 + 2u;
  TF_ROUND(13) TF_ROUND(15) TF_ROUND(26) TF_ROUND(6)
  x0 += k0; x1 += k1 + 3u;
  TF_ROUND(17) TF_ROUND(29) TF_ROUND(16) TF_ROUND(24)
  x0 += k1; x1 += k2 + 4u;
  TF_ROUND(13) TF_ROUND(15) TF_ROUND(26) TF_ROUND(6)
  x0 += k2; x1 += k0 + 5u;
#undef TF_ROUND
  return x0 ^ x1;
}

__device__ __forceinline__ uint16_t bf16_rne(float x) {
  uint32_t u = __float_as_uint(x);
  u += 0x7FFFu + ((u >> 16) & 1u);
  return (uint16_t)(u >> 16);
}

// ---------------------------------------------------------------------------
// 1) setup: blocks 0-97 zero deg_out+deg_in (25000 int4);
//           blocks 98-161 transpose W fp32 [k][n] -> Wt bf16 [n][k]
// ---------------------------------------------------------------------------
__global__ __launch_bounds__(256) void setup_kernel(
    const float* __restrict__ W, uint16_t* __restrict__ Wt,
    int4* __restrict__ zero_base) {
  const int bid = blockIdx.x;
  if (bid < 98) {
    const int t = bid * 256 + threadIdx.x;
    if (t < 25000) zero_base[t] = make_int4(0, 0, 0, 0);
  } else {
    const int t = (bid - 98) * 256 + threadIdx.x;  // 0..16383
    const int n = t >> 6;
    const int k4 = (t & 63) << 2;
    ushort4 p;
    p.x = bf16_rne(W[(size_t)(k4 + 0) * DDIM + n]);
    p.y = bf16_rne(W[(size_t)(k4 + 1) * DDIM + n]);
    p.z = bf16_rne(W[(size_t)(k4 + 2) * DDIM + n]);
    p.w = bf16_rne(W[(size_t)(k4 + 3) * DDIM + n]);
    *(ushort4*)(Wt + (size_t)n * DDIM + k4) = p;
  }
}

// ---------------------------------------------------------------------------
// 2) deg_out histogram only (no-return atomics, 4 edges/thread).
//    Unblocks fconv so it can fuse with fill+mask in the next kernel.
// ---------------------------------------------------------------------------
__global__ __launch_bounds__(256) void deghist_kernel(
    const int* __restrict__ src, int* __restrict__ deg_out) {
  const int base = (blockIdx.x * 256 + threadIdx.x) * 4;
  if (base < N_EDGES) {  // N_EDGES%4==0 -> full int4 in bounds
    const int4 s = *(const int4*)(src + base);
    atomicAdd(&deg_out[s.x], 1);
    atomicAdd(&deg_out[s.y], 1);
    atomicAdd(&deg_out[s.z], 1);
    atomicAdd(&deg_out[s.w], 1);
  }
}

// ---------------------------------------------------------------------------
// 3) MEGA-FUSED: fconv (blocks 0..6249)  ||  CSR fill (6250..6640)  ||
//    dropout mask (6641..8203).  Disjoint outputs; fill's atomic latency
//    overlaps under fconv's bandwidth and mask's VALU.
// ---------------------------------------------------------------------------
__global__ __launch_bounds__(256) void fused_prep_kernel(
    const float* __restrict__ feat, const int* __restrict__ src,
    const int* __restrict__ dst, const int* __restrict__ deg_out,
    int* __restrict__ deg_in, int* __restrict__ esrc,
    uint32_t* __restrict__ mask, uint16_t* __restrict__ featb) {
  const int bid = blockIdx.x;
  if (bid < FCONV_BLOCKS) {
    // featb = bf16(feat * rsqrt(max(deg_out,1)))
    const int t = bid * 256 + threadIdx.x;
    const size_t base = (size_t)t * 8;
    const int row = t >> 5;
    const float sc = rsqrtf(fmaxf((float)deg_out[row], 1.0f));
    const float4 a = *(const float4*)(feat + base);
    const float4 b = *(const float4*)(feat + base + 4);
    ushort4 lo, hi;
    lo.x = bf16_rne(a.x * sc); lo.y = bf16_rne(a.y * sc);
    lo.z = bf16_rne(a.z * sc); lo.w = bf16_rne(a.w * sc);
    hi.x = bf16_rne(b.x * sc); hi.y = bf16_rne(b.y * sc);
    hi.z = bf16_rne(b.z * sc); hi.w = bf16_rne(b.w * sc);
    *(ushort4*)(featb + base) = lo;
    *(ushort4*)(featb + base + 4) = hi;
  } else if (bid < FCONV_BLOCKS + FILL_BLOCKS) {
    // padded-CSR fill: deg_in atomic is the insertion cursor (4 edges/thread)
    const int base = ((bid - FCONV_BLOCKS) * 256 + threadIdx.x) * 4;
    if (base < N_EDGES) {
      const int4 s4 = *(const int4*)(src + base);
      const int4 d4 = *(const int4*)(dst + base);
      const int p0 = atomicAdd(&deg_in[d4.x], 1);
      const int p1 = atomicAdd(&deg_in[d4.y], 1);
      const int p2 = atomicAdd(&deg_in[d4.z], 1);
      const int p3 = atomicAdd(&deg_in[d4.w], 1);
      if (p0 < EDGE_CAP) esrc[(d4.x << 6) + p0] = s4.x;
      if (p1 < EDGE_CAP) esrc[(d4.y << 6) + p1] = s4.y;
      if (p2 < EDGE_CAP) esrc[(d4.z << 6) + p2] = s4.z;
      if (p3 < EDGE_CAP) esrc[(d4.w << 6) + p3] = s4.w;
    }
  } else {
    // dropout bitmask; keep(j) <=> (draw>>9) < 7549747 (== u<0.9f exactly)
    const uint32_t t =
        (uint32_t)(bid - FCONV_BLOCKS - FILL_BLOCKS) * 256u + (uint32_t)threadIdx.x;
    if (t < MASK_WORDS) {
      const uint32_t base = t * 32u;
      uint32_t w = 0u;
#pragma unroll
      for (uint32_t b = 0; b < 32u; ++b) {
        const uint32_t bits = threefry_draw_0_42(0u, base + b);
        w |= ((bits >> 9) < 7549747u) ? (1u << b) : 0u;
      }
      mask[t] = w;
    }
  }
}

// ---------------------------------------------------------------------------
// 4) pull-mode aggregate: HALF-WAVE (32 lanes) per node; lane owns 8 bf16
//    (uint4) of the 256-col row.  Up to 8 edge rows issued back-to-back
//    (8 KB in flight per wave) then accumulated; 4/2/1 ladder tail.
// ---------------------------------------------------------------------------
__device__ __forceinline__ void acc8(float* a, uint4 q) {
  a[0] += __uint_as_float(q.x << 16);
  a[1] += __uint_as_float(q.x & 0xFFFF0000u);
  a[2] += __uint_as_float(q.y << 16);
  a[3] += __uint_as_float(q.y & 0xFFFF0000u);
  a[4] += __uint_as_float(q.z << 16);
  a[5] += __uint_as_float(q.z & 0xFFFF0000u);
  a[6] += __uint_as_float(q.w << 16);
  a[7] += __uint_as_float(q.w & 0xFFFF0000u);
}

__global__ __launch_bounds__(256) void gather_kernel(
    const uint16_t* __restrict__ featb, const int* __restrict__ deg_in,
    const int* __restrict__ esrc, uint16_t* __restrict__ agg) {
  const int n = blockIdx.x * 8 + (threadIdx.x >> 5);
  if (n >= N_NODES) return;
  const int l32 = threadIdx.x & 31;
  const size_t coff = (size_t)(l32 << 3);
  const int beg = n << 6;
  const int cnt = min(deg_in[n], EDGE_CAP);

  float a[8] = {};
  int j = 0;
  for (; j + 8 <= cnt; j += 8) {
    const int4 e0 = *(const int4*)(esrc + beg + j);
    const int4 e1 = *(const int4*)(esrc + beg + j + 4);
    const uint4 q0 = *(const uint4*)(featb + (size_t)e0.x * DDIM + coff);
    const uint4 q1 = *(const uint4*)(featb + (size_t)e0.y * DDIM + coff);
    const uint4 q2 = *(const uint4*)(featb + (size_t)e0.z * DDIM + coff);
    const uint4 q3 = *(const uint4*)(featb + (size_t)e0.w * DDIM + coff);
    const uint4 q4 = *(const uint4*)(featb + (size_t)e1.x * DDIM + coff);
    const uint4 q5 = *(const uint4*)(featb + (size_t)e1.y * DDIM + coff);
    const uint4 q6 = *(const uint4*)(featb + (size_t)e1.z * DDIM + coff);
    const uint4 q7 = *(const uint4*)(featb + (size_t)e1.w * DDIM + coff);
    acc8(a, q0); acc8(a, q1); acc8(a, q2); acc8(a, q3);
    acc8(a, q4); acc8(a, q5); acc8(a, q6); acc8(a, q7);
  }
  if (j + 4 <= cnt) {
    const int4 e0 = *(const int4*)(esrc + beg + j);
    const uint4 q0 = *(const uint4*)(featb + (size_t)e0.x * DDIM + coff);
    const uint4 q1 = *(const uint4*)(featb + (size_t)e0.y * DDIM + coff);
    const uint4 q2 = *(const uint4*)(featb + (size_t)e0.z * DDIM + coff);
    const uint4 q3 = *(const uint4*)(featb + (size_t)e0.w * DDIM + coff);
    acc8(a, q0); acc8(a, q1); acc8(a, q2); acc8(a, q3);
    j += 4;
  }
  if (j + 2 <= cnt) {
    const int s0 = esrc[beg + j];
    const int s1 = esrc[beg + j + 1];
    const uint4 q0 = *(const uint4*)(featb + (size_t)s0 * DDIM + coff);
    const uint4 q1 = *(const uint4*)(featb + (size_t)s1 * DDIM + coff);
    acc8(a, q0); acc8(a, q1);
    j += 2;
  }
  if (j < cnt) {
    const int s0 = esrc[beg + j];
    const uint4 q0 = *(const uint4*)(featb + (size_t)s0 * DDIM + coff);
    acc8(a, q0);
  }

  uint4 p;
  p.x = (uint32_t)bf16_rne(a[0]) | ((uint32_t)bf16_rne(a[1]) << 16);
  p.y = (uint32_t)bf16_rne(a[2]) | ((uint32_t)bf16_rne(a[3]) << 16);
  p.z = (uint32_t)bf16_rne(a[4]) | ((uint32_t)bf16_rne(a[5]) << 16);
  p.w = (uint32_t)bf16_rne(a[6]) | ((uint32_t)bf16_rne(a[7]) << 16);
  *(uint4*)(agg + (size_t)n * DDIM + coff) = p;
}

// ---------------------------------------------------------------------------
// 5) out = dropout(relu((agg @ W) * rsqrt(max(deg_in,1)) + b))
//    MFMA bf16 16x16x32.  Block = 64 rows x 256 cols, 4 waves (wave: 64x64).
//    A staged once in LDS (37 KB -> 4 blocks/CU); B direct from L2 Wt.
// ---------------------------------------------------------------------------
#define APAD 280  // shorts per As row (560 B, 16B-aligned)
__global__ __launch_bounds__(256, 4) void gemm_mfma_kernel(
    const uint16_t* __restrict__ agg, const uint16_t* __restrict__ Wt,
    const float* __restrict__ bias, const int* __restrict__ deg_in,
    const uint32_t* __restrict__ mask, float* __restrict__ out) {
  __shared__ short As[64 * APAD];
  __shared__ float sdeg[64];
  __shared__ float sbias[256];

  const int tid = threadIdx.x;
  const int r0 = blockIdx.x * 64;
  const int lane = tid & 63;
  const int seg = lane >> 4;  // k-segment 0..3
  const int l15 = lane & 15;
  const int wc = tid >> 6;  // wave -> col panel (64 cols each)

  sbias[tid] = bias[tid];
  if (tid < 64) {
    const int r = r0 + tid;
    sdeg[tid] = (r < N_NODES) ? rsqrtf(fmaxf((float)deg_in[r], 1.0f)) : 0.0f;
  }

  // stage A panel: 64 rows x 256 k bf16 (2048 x 16B chunks, coalesced)
  {
    const uint16_t* ap = agg + (size_t)r0 * DDIM;
#pragma unroll
    for (int it = 0; it < 8; ++it) {
      const int c = tid + 256 * it;
      const int row = c >> 5;        // 32 chunks per row
      const int k8 = (c & 31) << 3;  // 0,8,...,248
      int4 v = make_int4(0, 0, 0, 0);
      if (r0 + row < N_NODES) v = *(const int4*)(ap + (size_t)row * DDIM + k8);
      *(int4*)&As[row * APAD + k8] = v;
    }
  }
  __syncthreads();

  const uint16_t* wt_base = Wt + (size_t)(wc * 64 + l15) * DDIM + seg * 8;

  f32x4 acc[4][4] = {};
#pragma unroll
  for (int kkI = 0; kkI < 8; ++kkI) {
    const int kk = kkI * 32;
    bf16x8 a[4], b[4];
#pragma unroll
    for (int m = 0; m < 4; ++m)
      a[m] = *(const bf16x8*)&As[(m * 16 + l15) * APAD + kk + seg * 8];
#pragma unroll
    for (int n = 0; n < 4; ++n)
      b[n] = *(const bf16x8*)(wt_base + n * 16 * DDIM + kk);
#pragma unroll
    for (int m = 0; m < 4; ++m)
#pragma unroll
      for (int n = 0; n < 4; ++n)
        acc[m][n] = __builtin_amdgcn_mfma_f32_16x16x32_bf16(a[m], b[n], acc[m][n], 0, 0, 0);
  }

  // epilogue: C/D layout col = lane&15, row = seg*4 + reg
  constexpr float INV09 = 1.0f / 0.9f;
#pragma unroll
  for (int m = 0; m < 4; ++m) {
#pragma unroll
    for (int r = 0; r < 4; ++r) {
      const int lrow = m * 16 + seg * 4 + r;
      const int row = r0 + lrow;
      if (row >= N_NODES) continue;
      const float s = sdeg[lrow];
      const uint32_t w0 = mask[row * 8 + wc * 2];      // cols wc*64 .. +31
      const uint32_t w1 = mask[row * 8 + wc * 2 + 1];  // cols wc*64+32 .. +63
#pragma unroll
      for (int n = 0; n < 4; ++n) {
        const int col = wc * 64 + n * 16 + l15;
        float v = fmaxf(acc[m][n][r] * s + sbias[col], 0.0f);
        const uint32_t w = (n < 2) ? w0 : w1;
        const uint32_t bit = (uint32_t)((n & 1) * 16 + l15);
        out[(size_t)row * DDIM + col] = ((w >> bit) & 1u) ? v * INV09 : 0.0f;
      }
    }
  }
}

// ---------------------------------------------------------------------------
// ws layout (bytes; ws_size ~268 MB per harness poison fill):
//   deg_out   @ 0          (200000)
//   deg_in    @ 200000     (200000)
//   esrc      @ 400000     (12800000)  padded CSR [n][64]
//   Wt bf16   @ 13200000   (131072)
//   featb bf16@ 13331072   (25600000)
//   mask u32  @ 38931072   (1600000)
//   agg bf16  @ 40531072   (25600000)  total ~66 MB
// ---------------------------------------------------------------------------
extern "C" void kernel_launch(void* const* d_in, const int* in_sizes, int n_in,
                              void* d_out, int out_size, void* d_ws, size_t ws_size,
                              hipStream_t stream) {
  const float* feat = (const float*)d_in[0];
  const float* W = (const float*)d_in[1];
  const float* bias = (const float*)d_in[2];
  const int* src = (const int*)d_in[3];
  const int* dst = (const int*)d_in[4];
  float* out = (float*)d_out;

  char* ws = (char*)d_ws;
  int* deg_out = (int*)(ws + 0);
  int* deg_in = (int*)(ws + 200000);
  int* esrc = (int*)(ws + 400000);
  uint16_t* Wt = (uint16_t*)(ws + 13200000);
  uint16_t* featb = (uint16_t*)(ws + 13331072);
  uint32_t* mask = (uint32_t*)(ws + 38931072);
  uint16_t* agg = (uint16_t*)(ws + 40531072);

  setup_kernel<<<162, 256, 0, stream>>>(W, Wt, (int4*)d_ws);
  deghist_kernel<<<391, 256, 0, stream>>>(src, deg_out);
  fused_prep_kernel<<<FCONV_BLOCKS + FILL_BLOCKS + MASK_BLOCKS, 256, 0, stream>>>(
      feat, src, dst, deg_out, deg_in, esrc, mask, featb);
  gather_kernel<<<(N_NODES + 7) / 8, 256, 0, stream>>>(featb, deg_in, esrc, agg);
  gemm_mfma_kernel<<<(N_NODES + 63) / 64, 256, 0, stream>>>(agg, Wt, bias, deg_in, mask, out);
}

// Round 16
// 117.503 us; speedup vs baseline: 1.2781x; 1.1035x over previous
//
#include <hip/hip_runtime.h>
#include <stdint.h>

#define N_NODES 50000
#define N_EDGES 400000
#define DDIM 256
#define MASK_WORDS 400000  // 50000*256/32
#define EDGE_CAP 64        // padded CSR row capacity (max in-degree ~30)
#define EDGE_BLOCKS 391    // ceil(400000/4/256), 4 edges per thread
#define MASK_BLOCKS 1563   // ceil(400000/256)
#define FCONV_BLOCKS 6250  // 50000*256/8 / 256

typedef __attribute__((ext_vector_type(8))) short bf16x8;
typedef __attribute__((ext_vector_type(4))) float f32x4;

// ---------------------------------------------------------------------------
// JAX threefry2x32, key = (0, 42).  Partitionable scheme (verified round 5):
// element with flat index j uses counter (0, j); draw = out0 ^ out1.
// ---------------------------------------------------------------------------
__device__ __forceinline__ uint32_t rotl32(uint32_t x, uint32_t r) {
  return (x << r) | (x >> (32u - r));
}

__device__ __forceinline__ uint32_t threefry_draw_0_42(uint32_t x0, uint32_t x1) {
  const uint32_t k0 = 0u, k1 = 42u;
  const uint32_t k2 = k0 ^ k1 ^ 0x1BD11BDAu;
  x0 += k0;
  x1 += k1;
#define TF_ROUND(r)          \
  {                          \
    x0 += x1;                \
    x1 = rotl32(x1, r);      \
    x1 ^= x0;                \
  }
  TF_ROUND(13) TF_ROUND(15) TF_ROUND(26) TF_ROUND(6)
  x0 += k1; x1 += k2 + 1u;
  TF_ROUND(17) TF_ROUND(29) TF_ROUND(16) TF_ROUND(24)
  x0 += k2; x1 += k0 + 2u;
  TF_ROUND(13) TF_ROUND(15) TF_ROUND(26) TF_ROUND(6)
  x0 += k0; x1 += k1 + 3u;
  TF_ROUND(17) TF_ROUND(29) TF_ROUND(16) TF_ROUND(24)
  x0 += k1; x1 += k2 + 4u;
  TF_ROUND(13) TF_ROUND(15) TF_ROUND(26) TF_ROUND(6)
  x0 += k2; x1 += k0 + 5u;
#undef TF_ROUND
  return x0 ^ x1;
}

__device__ __forceinline__ uint16_t bf16_rne(float x) {
  uint32_t u = __float_as_uint(x);
  u += 0x7FFFu + ((u >> 16) & 1u);
  return (uint16_t)(u >> 16);
}

// ---------------------------------------------------------------------------
// 1) setup: blocks 0-97 zero deg_out+deg_in (25000 int4);
//           blocks 98-161 transpose W fp32 [k][n] -> Wt bf16 [n][k]
// ---------------------------------------------------------------------------
__global__ __launch_bounds__(256) void setup_kernel(
    const float* __restrict__ W, uint16_t* __restrict__ Wt,
    int4* __restrict__ zero_base) {
  const int bid = blockIdx.x;
  if (bid < 98) {
    const int t = bid * 256 + threadIdx.x;
    if (t < 25000) zero_base[t] = make_int4(0, 0, 0, 0);
  } else {
    const int t = (bid - 98) * 256 + threadIdx.x;  // 0..16383
    const int n = t >> 6;
    const int k4 = (t & 63) << 2;
    ushort4 p;
    p.x = bf16_rne(W[(size_t)(k4 + 0) * DDIM + n]);
    p.y = bf16_rne(W[(size_t)(k4 + 1) * DDIM + n]);
    p.z = bf16_rne(W[(size_t)(k4 + 2) * DDIM + n]);
    p.w = bf16_rne(W[(size_t)(k4 + 3) * DDIM + n]);
    *(ushort4*)(Wt + (size_t)n * DDIM + k4) = p;
  }
}

// ---------------------------------------------------------------------------
// 2) MEGA-FUSED prep.  Block ranges (latency-bound edges FIRST):
//      [0, 391)              single edge pass: deg_out histogram (no-return
//                            atomic) + deg_in cursor atomic + esrc store
//      [391, 1954)           dropout bitmask (pure VALU)
//      [1954, 8204)          featb = bf16(feat)  (pure convert, BW-bound)
//    Disjoint outputs; no section reads another's output.
// ---------------------------------------------------------------------------
__global__ __launch_bounds__(256) void mega_prep_kernel(
    const float* __restrict__ feat, const int* __restrict__ src,
    const int* __restrict__ dst, int* __restrict__ deg_out,
    int* __restrict__ deg_in, int* __restrict__ esrc,
    uint32_t* __restrict__ mask, uint16_t* __restrict__ featb) {
  const int bid = blockIdx.x;
  if (bid < EDGE_BLOCKS) {
    const int base = (bid * 256 + threadIdx.x) * 4;
    if (base < N_EDGES) {  // N_EDGES%4==0 -> full int4 in bounds
      const int4 s4 = *(const int4*)(src + base);
      const int4 d4 = *(const int4*)(dst + base);
      atomicAdd(&deg_out[s4.x], 1);
      atomicAdd(&deg_out[s4.y], 1);
      atomicAdd(&deg_out[s4.z], 1);
      atomicAdd(&deg_out[s4.w], 1);
      const int p0 = atomicAdd(&deg_in[d4.x], 1);
      const int p1 = atomicAdd(&deg_in[d4.y], 1);
      const int p2 = atomicAdd(&deg_in[d4.z], 1);
      const int p3 = atomicAdd(&deg_in[d4.w], 1);
      if (p0 < EDGE_CAP) esrc[(d4.x << 6) + p0] = s4.x;
      if (p1 < EDGE_CAP) esrc[(d4.y << 6) + p1] = s4.y;
      if (p2 < EDGE_CAP) esrc[(d4.z << 6) + p2] = s4.z;
      if (p3 < EDGE_CAP) esrc[(d4.w << 6) + p3] = s4.w;
    }
  } else if (bid < EDGE_BLOCKS + MASK_BLOCKS) {
    // dropout bitmask; keep(j) <=> (draw>>9) < 7549747 (== u<0.9f exactly)
    const uint32_t t =
        (uint32_t)(bid - EDGE_BLOCKS) * 256u + (uint32_t)threadIdx.x;
    if (t < MASK_WORDS) {
      const uint32_t base = t * 32u;
      uint32_t w = 0u;
#pragma unroll
      for (uint32_t b = 0; b < 32u; ++b) {
        const uint32_t bits = threefry_draw_0_42(0u, base + b);
        w |= ((bits >> 9) < 7549747u) ? (1u << b) : 0u;
      }
      mask[t] = w;
    }
  } else {
    // featb = bf16(feat)  (unscaled; gather applies rsqrt(deg_out) per edge)
    const int t = (bid - EDGE_BLOCKS - MASK_BLOCKS) * 256 + threadIdx.x;
    const size_t base = (size_t)t * 8;
    const float4 a = *(const float4*)(feat + base);
    const float4 b = *(const float4*)(feat + base + 4);
    ushort4 lo, hi;
    lo.x = bf16_rne(a.x); lo.y = bf16_rne(a.y);
    lo.z = bf16_rne(a.z); lo.w = bf16_rne(a.w);
    hi.x = bf16_rne(b.x); hi.y = bf16_rne(b.y);
    hi.z = bf16_rne(b.z); hi.w = bf16_rne(b.w);
    *(ushort4*)(featb + base) = lo;
    *(ushort4*)(featb + base + 4) = hi;
  }
}

// ---------------------------------------------------------------------------
// 3) pull-mode aggregate: HALF-WAVE (32 lanes) per node; lane owns 8 bf16
//    (uint4) of the 256-col row.  8 edge rows + their deg scales issued
//    back-to-back, fp32 fma accumulate; 4/2/1 ladder tail.
//    scale = rsqrt(max(deg_out[src],1)) applied per edge (fp32).
// ---------------------------------------------------------------------------
__device__ __forceinline__ void acc8s(float* a, uint4 q, float sc) {
  a[0] = fmaf(__uint_as_float(q.x << 16), sc, a[0]);
  a[1] = fmaf(__uint_as_float(q.x & 0xFFFF0000u), sc, a[1]);
  a[2] = fmaf(__uint_as_float(q.y << 16), sc, a[2]);
  a[3] = fmaf(__uint_as_float(q.y & 0xFFFF0000u), sc, a[3]);
  a[4] = fmaf(__uint_as_float(q.z << 16), sc, a[4]);
  a[5] = fmaf(__uint_as_float(q.z & 0xFFFF0000u), sc, a[5]);
  a[6] = fmaf(__uint_as_float(q.w << 16), sc, a[6]);
  a[7] = fmaf(__uint_as_float(q.w & 0xFFFF0000u), sc, a[7]);
}

__device__ __forceinline__ float dscale(const int* deg, int s) {
  return rsqrtf(fmaxf((float)deg[s], 1.0f));
}

__global__ __launch_bounds__(256) void gather_kernel(
    const uint16_t* __restrict__ featb, const int* __restrict__ deg_out,
    const int* __restrict__ deg_in, const int* __restrict__ esrc,
    uint16_t* __restrict__ agg) {
  const int n = blockIdx.x * 8 + (threadIdx.x >> 5);
  if (n >= N_NODES) return;
  const int l32 = threadIdx.x & 31;
  const size_t coff = (size_t)(l32 << 3);
  const int beg = n << 6;
  const int cnt = min(deg_in[n], EDGE_CAP);

  float a[8] = {};
  int j = 0;
  for (; j + 8 <= cnt; j += 8) {
    const int4 e0 = *(const int4*)(esrc + beg + j);
    const int4 e1 = *(const int4*)(esrc + beg + j + 4);
    const uint4 q0 = *(const uint4*)(featb + (size_t)e0.x * DDIM + coff);
    const uint4 q1 = *(const uint4*)(featb + (size_t)e0.y * DDIM + coff);
    const uint4 q2 = *(const uint4*)(featb + (size_t)e0.z * DDIM + coff);
    const uint4 q3 = *(const uint4*)(featb + (size_t)e0.w * DDIM + coff);
    const uint4 q4 = *(const uint4*)(featb + (size_t)e1.x * DDIM + coff);
    const uint4 q5 = *(const uint4*)(featb + (size_t)e1.y * DDIM + coff);
    const uint4 q6 = *(const uint4*)(featb + (size_t)e1.z * DDIM + coff);
    const uint4 q7 = *(const uint4*)(featb + (size_t)e1.w * DDIM + coff);
    const float s0 = dscale(deg_out, e0.x);
    const float s1 = dscale(deg_out, e0.y);
    const float s2 = dscale(deg_out, e0.z);
    const float s3 = dscale(deg_out, e0.w);
    const float s4 = dscale(deg_out, e1.x);
    const float s5 = dscale(deg_out, e1.y);
    const float s6 = dscale(deg_out, e1.z);
    const float s7 = dscale(deg_out, e1.w);
    acc8s(a, q0, s0); acc8s(a, q1, s1); acc8s(a, q2, s2); acc8s(a, q3, s3);
    acc8s(a, q4, s4); acc8s(a, q5, s5); acc8s(a, q6, s6); acc8s(a, q7, s7);
  }
  if (j + 4 <= cnt) {
    const int4 e0 = *(const int4*)(esrc + beg + j);
    const uint4 q0 = *(const uint4*)(featb + (size_t)e0.x * DDIM + coff);
    const uint4 q1 = *(const uint4*)(featb + (size_t)e0.y * DDIM + coff);
    const uint4 q2 = *(const uint4*)(featb + (size_t)e0.z * DDIM + coff);
    const uint4 q3 = *(const uint4*)(featb + (size_t)e0.w * DDIM + coff);
    const float s0 = dscale(deg_out, e0.x);
    const float s1 = dscale(deg_out, e0.y);
    const float s2 = dscale(deg_out, e0.z);
    const float s3 = dscale(deg_out, e0.w);
    acc8s(a, q0, s0); acc8s(a, q1, s1); acc8s(a, q2, s2); acc8s(a, q3, s3);
    j += 4;
  }
  if (j + 2 <= cnt) {
    const int s0i = esrc[beg + j];
    const int s1i = esrc[beg + j + 1];
    const uint4 q0 = *(const uint4*)(featb + (size_t)s0i * DDIM + coff);
    const uint4 q1 = *(const uint4*)(featb + (size_t)s1i * DDIM + coff);
    acc8s(a, q0, dscale(deg_out, s0i));
    acc8s(a, q1, dscale(deg_out, s1i));
    j += 2;
  }
  if (j < cnt) {
    const int s0i = esrc[beg + j];
    const uint4 q0 = *(const uint4*)(featb + (size_t)s0i * DDIM + coff);
    acc8s(a, q0, dscale(deg_out, s0i));
  }

  uint4 p;
  p.x = (uint32_t)bf16_rne(a[0]) | ((uint32_t)bf16_rne(a[1]) << 16);
  p.y = (uint32_t)bf16_rne(a[2]) | ((uint32_t)bf16_rne(a[3]) << 16);
  p.z = (uint32_t)bf16_rne(a[4]) | ((uint32_t)bf16_rne(a[5]) << 16);
  p.w = (uint32_t)bf16_rne(a[6]) | ((uint32_t)bf16_rne(a[7]) << 16);
  *(uint4*)(agg + (size_t)n * DDIM + coff) = p;
}

// ---------------------------------------------------------------------------
// 4) out = dropout(relu((agg @ W) * rsqrt(max(deg_in,1)) + b))
//    MFMA bf16 16x16x32.  Block = 64 rows x 256 cols, 4 waves (wave: 64x64).
//    A staged once in LDS (37 KB -> 4 blocks/CU); B direct from L2 Wt.
// ---------------------------------------------------------------------------
#define APAD 280  // shorts per As row (560 B, 16B-aligned)
__global__ __launch_bounds__(256, 4) void gemm_mfma_kernel(
    const uint16_t* __restrict__ agg, const uint16_t* __restrict__ Wt,
    const float* __restrict__ bias, const int* __restrict__ deg_in,
    const uint32_t* __restrict__ mask, float* __restrict__ out) {
  __shared__ short As[64 * APAD];
  __shared__ float sdeg[64];
  __shared__ float sbias[256];

  const int tid = threadIdx.x;
  const int r0 = blockIdx.x * 64;
  const int lane = tid & 63;
  const int seg = lane >> 4;  // k-segment 0..3
  const int l15 = lane & 15;
  const int wc = tid >> 6;  // wave -> col panel (64 cols each)

  sbias[tid] = bias[tid];
  if (tid < 64) {
    const int r = r0 + tid;
    sdeg[tid] = (r < N_NODES) ? rsqrtf(fmaxf((float)deg_in[r], 1.0f)) : 0.0f;
  }

  // stage A panel: 64 rows x 256 k bf16 (2048 x 16B chunks, coalesced)
  {
    const uint16_t* ap = agg + (size_t)r0 * DDIM;
#pragma unroll
    for (int it = 0; it < 8; ++it) {
      const int c = tid + 256 * it;
      const int row = c >> 5;        // 32 chunks per row
      const int k8 = (c & 31) << 3;  // 0,8,...,248
      int4 v = make_int4(0, 0, 0, 0);
      if (r0 + row < N_NODES) v = *(const int4*)(ap + (size_t)row * DDIM + k8);
      *(int4*)&As[row * APAD + k8] = v;
    }
  }
  __syncthreads();

  const uint16_t* wt_base = Wt + (size_t)(wc * 64 + l15) * DDIM + seg * 8;

  f32x4 acc[4][4] = {};
#pragma unroll
  for (int kkI = 0; kkI < 8; ++kkI) {
    const int kk = kkI * 32;
    bf16x8 a[4], b[4];
#pragma unroll
    for (int m = 0; m < 4; ++m)
      a[m] = *(const bf16x8*)&As[(m * 16 + l15) * APAD + kk + seg * 8];
#pragma unroll
    for (int n = 0; n < 4; ++n)
      b[n] = *(const bf16x8*)(wt_base + n * 16 * DDIM + kk);
#pragma unroll
    for (int m = 0; m < 4; ++m)
#pragma unroll
      for (int n = 0; n < 4; ++n)
        acc[m][n] = __builtin_amdgcn_mfma_f32_16x16x32_bf16(a[m], b[n], acc[m][n], 0, 0, 0);
  }

  // epilogue: C/D layout col = lane&15, row = seg*4 + reg
  constexpr float INV09 = 1.0f / 0.9f;
#pragma unroll
  for (int m = 0; m < 4; ++m) {
#pragma unroll
    for (int r = 0; r < 4; ++r) {
      const int lrow = m * 16 + seg * 4 + r;
      const int row = r0 + lrow;
      if (row >= N_NODES) continue;
      const float s = sdeg[lrow];
      const uint32_t w0 = mask[row * 8 + wc * 2];      // cols wc*64 .. +31
      const uint32_t w1 = mask[row * 8 + wc * 2 + 1];  // cols wc*64+32 .. +63
#pragma unroll
      for (int n = 0; n < 4; ++n) {
        const int col = wc * 64 + n * 16 + l15;
        float v = fmaxf(acc[m][n][r] * s + sbias[col], 0.0f);
        const uint32_t w = (n < 2) ? w0 : w1;
        const uint32_t bit = (uint32_t)((n & 1) * 16 + l15);
        out[(size_t)row * DDIM + col] = ((w >> bit) & 1u) ? v * INV09 : 0.0f;
      }
    }
  }
}

// ---------------------------------------------------------------------------
// ws layout (bytes; ws_size ~268 MB per harness poison fill):
//   deg_out   @ 0          (200000)
//   deg_in    @ 200000     (200000)
//   esrc      @ 400000     (12800000)  padded CSR [n][64]
//   Wt bf16   @ 13200000   (131072)
//   featb bf16@ 13331072   (25600000)
//   mask u32  @ 38931072   (1600000)
//   agg bf16  @ 40531072   (25600000)  total ~66 MB
// ---------------------------------------------------------------------------
extern "C" void kernel_launch(void* const* d_in, const int* in_sizes, int n_in,
                              void* d_out, int out_size, void* d_ws, size_t ws_size,
                              hipStream_t stream) {
  const float* feat = (const float*)d_in[0];
  const float* W = (const float*)d_in[1];
  const float* bias = (const float*)d_in[2];
  const int* src = (const int*)d_in[3];
  const int* dst = (const int*)d_in[4];
  float* out = (float*)d_out;

  char* ws = (char*)d_ws;
  int* deg_out = (int*)(ws + 0);
  int* deg_in = (int*)(ws + 200000);
  int* esrc = (int*)(ws + 400000);
  uint16_t* Wt = (uint16_t*)(ws + 13200000);
  uint16_t* featb = (uint16_t*)(ws + 13331072);
  uint32_t* mask = (uint32_t*)(ws + 38931072);
  uint16_t* agg = (uint16_t*)(ws + 40531072);

  setup_kernel<<<162, 256, 0, stream>>>(W, Wt, (int4*)d_ws);
  mega_prep_kernel<<<EDGE_BLOCKS + MASK_BLOCKS + FCONV_BLOCKS, 256, 0, stream>>>(
      feat, src, dst, deg_out, deg_in, esrc, mask, featb);
  gather_kernel<<<(N_NODES + 7) / 8, 256, 0, stream>>>(featb, deg_out, deg_in, esrc, agg);
  gemm_mfma_kernel<<<(N_NODES + 63) / 64, 256, 0, stream>>>(agg, Wt, bias, deg_in, mask, out);
}